// Round 1
// baseline (227.865 us; speedup 1.0000x reference)
//
#include <hip/hip_runtime.h>
#include <math.h>

constexpr int NB = 256;   // batch
constexpr int NS = 128;   // seq len
constexpr int NE = 256;   // embed dim
constexpr int NT = 32;    // output classes
constexpr int DIN = 260;  // E + H

__device__ __forceinline__ float fast_sigmoid(float x) {
    return 1.0f / (1.0f + __expf(-x));
}
__device__ __forceinline__ float fast_tanh(float x) {
    x = fminf(fmaxf(x, -15.0f), 15.0f);
    float e = __expf(2.0f * x);
    return (e - 1.0f) / (e + 1.0f);
}

// ---------------- Kernel 1: x-part of all 4 gate preactivations ----------------
// xpart[s][b][16] = emb[x[b,s]] @ W{f,i,u,o}[:, :256].T + bias   (gate-major: f0..f3,i0..i3,u0..u3,o0..o3)
__global__ __launch_bounds__(256) void k_embed(
    const int* __restrict__ x, const float* __restrict__ emb,
    const float* __restrict__ Wf, const float* __restrict__ bf,
    const float* __restrict__ Wi, const float* __restrict__ bi,
    const float* __restrict__ Wu, const float* __restrict__ bu,
    const float* __restrict__ Wo, const float* __restrict__ bo,
    float* __restrict__ xpart)
{
    __shared__ float Wlds[16][256];
    __shared__ float blds[16];
    int tid = threadIdx.x;
    for (int i = tid; i < 16 * 256; i += 256) {
        int w16 = i >> 8;
        int e = i & 255;
        const float* Wp = (w16 < 8) ? ((w16 < 4) ? Wf : Wi) : ((w16 < 12) ? Wu : Wo);
        Wlds[w16][e] = Wp[(w16 & 3) * DIN + e];
    }
    if (tid < 16) {
        const float* bp = (tid < 8) ? ((tid < 4) ? bf : bi) : ((tid < 12) ? bu : bo);
        blds[tid] = bp[tid & 3];
    }
    __syncthreads();

    int wave = tid >> 6;
    int lane = tid & 63;
    int row0 = blockIdx.x * 32 + wave * 8;  // rows r = s*256 + b
    for (int i = 0; i < 8; ++i) {
        int r = row0 + i;
        int b = r & 255, s = r >> 8;
        int tok = x[b * NS + s];
        float4 ev = *(const float4*)(emb + (size_t)tok * NE + lane * 4);
        float acc[16];
        #pragma unroll
        for (int j = 0; j < 16; ++j) {
            float4 wv = *(const float4*)(&Wlds[j][lane * 4]);
            acc[j] = ev.x * wv.x + ev.y * wv.y + ev.z * wv.z + ev.w * wv.w;
        }
        #pragma unroll
        for (int m = 1; m < 64; m <<= 1) {
            #pragma unroll
            for (int j = 0; j < 16; ++j)
                acc[j] += __shfl_xor(acc[j], m, 64);
        }
        if (lane < 16)
            xpart[(size_t)r * 16 + lane] = acc[lane] + blds[lane];
    }
}

// ---------------- Kernel 2: serial LSTM recurrence with analytic quantum gate ----------------
// qgate(a0..a3): out0=c1c2c3, out1=c0c1, out2=c0c1c2, out3=c0c1c2c3  (ck = cos(ak))
__global__ __launch_bounds__(64) void k_recur(
    const float* __restrict__ Wf, const float* __restrict__ Wi,
    const float* __restrict__ Wu, const float* __restrict__ Wo,
    const float* __restrict__ thf, const float* __restrict__ thi,
    const float* __restrict__ thu, const float* __restrict__ tho,
    const float* __restrict__ xpart, float* __restrict__ hs)
{
    int b = blockIdx.x * 64 + threadIdx.x;

    float Wh[4][4][4];  // [gate][h][j] = W[h*260 + 256 + j]
    float th[4][4];
    #pragma unroll
    for (int g = 0; g < 4; ++g) {
        const float* Wp = (g == 0) ? Wf : (g == 1) ? Wi : (g == 2) ? Wu : Wo;
        const float* tp = (g == 0) ? thf : (g == 1) ? thi : (g == 2) ? thu : tho;
        #pragma unroll
        for (int hh = 0; hh < 4; ++hh) {
            #pragma unroll
            for (int j = 0; j < 4; ++j)
                Wh[g][hh][j] = Wp[hh * DIN + 256 + j];
            th[g][hh] = tp[hh];
        }
    }

    float h[4] = {0.f, 0.f, 0.f, 0.f};
    float c[4] = {0.f, 0.f, 0.f, 0.f};

    for (int s = 0; s < NS; ++s) {
        const float4* xp = (const float4*)(xpart + ((size_t)s * NB + b) * 16);
        float4 x0 = xp[0], x1 = xp[1], x2 = xp[2], x3 = xp[3];
        float xs[16] = {x0.x, x0.y, x0.z, x0.w, x1.x, x1.y, x1.z, x1.w,
                        x2.x, x2.y, x2.z, x2.w, x3.x, x3.y, x3.z, x3.w};
        float q[4][4];
        #pragma unroll
        for (int g = 0; g < 4; ++g) {
            float a[4];
            #pragma unroll
            for (int hh = 0; hh < 4; ++hh) {
                a[hh] = xs[g * 4 + hh] + th[g][hh]
                      + Wh[g][hh][0] * h[0] + Wh[g][hh][1] * h[1]
                      + Wh[g][hh][2] * h[2] + Wh[g][hh][3] * h[3];
            }
            float c0 = __cosf(a[0]), c1 = __cosf(a[1]);
            float c2 = __cosf(a[2]), c3 = __cosf(a[3]);
            q[g][1] = c0 * c1;
            q[g][2] = q[g][1] * c2;
            q[g][3] = q[g][2] * c3;
            q[g][0] = c1 * c2 * c3;
        }
        #pragma unroll
        for (int j = 0; j < 4; ++j) {
            float fv = fast_sigmoid(q[0][j]);
            float iv = fast_sigmoid(q[1][j]);
            float gv = fast_tanh(q[2][j]);
            float ov = fast_sigmoid(q[3][j]);
            c[j] = fv * c[j] + iv * gv;
            h[j] = ov * fast_tanh(c[j]);
        }
        *(float4*)(hs + ((size_t)s * NB + b) * 4) = make_float4(h[0], h[1], h[2], h[3]);
    }
}

// ---------------- Kernel 3: logits + log_softmax ----------------
// 8 lanes per (b,s) row; lane k computes logits [4k..4k+3]
__global__ __launch_bounds__(256) void k_out(
    const float* __restrict__ hs, const float* __restrict__ Wc,
    const float* __restrict__ bc, float* __restrict__ out)
{
    int gtid = blockIdx.x * 256 + threadIdx.x;
    int r = gtid >> 3;     // r = b*S + s
    int lr = gtid & 7;
    if (r >= NB * NS) return;
    int b = r >> 7, s = r & 127;
    float4 h = *(const float4*)(hs + ((size_t)s * NB + b) * 4);
    float l[4];
    #pragma unroll
    for (int k = 0; k < 4; ++k) {
        int t = lr * 4 + k;
        float4 w = *(const float4*)(Wc + t * 4);
        l[k] = bc[t] + w.x * h.x + w.y * h.y + w.z * h.z + w.w * h.w;
    }
    float m = fmaxf(fmaxf(l[0], l[1]), fmaxf(l[2], l[3]));
    #pragma unroll
    for (int msk = 1; msk < 8; msk <<= 1)
        m = fmaxf(m, __shfl_xor(m, msk, 64));
    float sum = 0.f;
    #pragma unroll
    for (int k = 0; k < 4; ++k)
        sum += __expf(l[k] - m);
    #pragma unroll
    for (int msk = 1; msk < 8; msk <<= 1)
        sum += __shfl_xor(sum, msk, 64);
    float lse = __logf(sum);
    float4 o;
    o.x = l[0] - m - lse;
    o.y = l[1] - m - lse;
    o.z = l[2] - m - lse;
    o.w = l[3] - m - lse;
    *(float4*)(out + (size_t)r * 32 + lr * 4) = o;
}

extern "C" void kernel_launch(void* const* d_in, const int* in_sizes, int n_in,
                              void* d_out, int out_size, void* d_ws, size_t ws_size,
                              hipStream_t stream) {
    const int*   x   = (const int*)d_in[0];
    const float* emb = (const float*)d_in[1];
    const float* Wf  = (const float*)d_in[2];
    const float* bf  = (const float*)d_in[3];
    const float* Wi  = (const float*)d_in[4];
    const float* bi  = (const float*)d_in[5];
    const float* Wu  = (const float*)d_in[6];
    const float* bu  = (const float*)d_in[7];
    const float* Wo  = (const float*)d_in[8];
    const float* bo  = (const float*)d_in[9];
    const float* thf = (const float*)d_in[10];
    const float* thi = (const float*)d_in[11];
    const float* thu = (const float*)d_in[12];
    const float* tho = (const float*)d_in[13];
    const float* Wc  = (const float*)d_in[14];
    const float* bc  = (const float*)d_in[15];
    float* out = (float*)d_out;

    float* xpart = (float*)d_ws;                    // [S][B][16]  2 MB
    float* hs    = xpart + (size_t)NS * NB * 16;    // [S][B][4]   512 KB

    k_embed<<<1024, 256, 0, stream>>>(x, emb, Wf, bf, Wi, bi, Wu, bu, Wo, bo, xpart);
    k_recur<<<4, 64, 0, stream>>>(Wf, Wi, Wu, Wo, thf, thi, thu, tho, xpart, hs);
    k_out<<<1024, 256, 0, stream>>>(hs, Wc, bc, out);
}

// Round 2
// 90.800 us; speedup vs baseline: 2.5095x; 2.5095x over previous
//
#include <hip/hip_runtime.h>
#include <math.h>

constexpr int NB = 256;   // batch
constexpr int NS = 128;   // seq len
constexpr int NE = 256;   // embed dim
constexpr int DIN = 260;  // E + H

// ---------- fast primitives ----------
__device__ __forceinline__ float rcp_fast(float x) {
#if __has_builtin(__builtin_amdgcn_rcpf)
    return __builtin_amdgcn_rcpf(x);
#else
    return 1.0f / x;
#endif
}

#if __has_builtin(__builtin_amdgcn_mov_dpp)
#define DPP_XOR1(x) __int_as_float(__builtin_amdgcn_mov_dpp(__float_as_int(x), 0xB1, 0xF, 0xF, true))
#define DPP_XOR2(x) __int_as_float(__builtin_amdgcn_mov_dpp(__float_as_int(x), 0x4E, 0xF, 0xF, true))
#define DPP_XOR3(x) __int_as_float(__builtin_amdgcn_mov_dpp(__float_as_int(x), 0x1B, 0xF, 0xF, true))
#else
#define DPP_XOR1(x) __shfl_xor((x), 1, 64)
#define DPP_XOR2(x) __shfl_xor((x), 2, 64)
#define DPP_XOR3(x) __shfl_xor((x), 3, 64)
#endif

// Lambert continued-fraction tanh, exact-integer coeffs.
// |err| ~1e-7 on [-1,1], ~2e-5 at |y|=3. No exp; one v_rcp.
__device__ __forceinline__ float tanh_cf(float y) {
    float w = y * y;
    float num = y * fmaf(fmaf(21.0f, w, 1260.0f), w, 10395.0f);
    float den = fmaf(fmaf(w + 210.0f, w, 4725.0f), w, 10395.0f);
    return num * rcp_fast(den);
}

__device__ __forceinline__ float sel4f(float v0, float v1, float v2, float v3,
                                       bool bit0, bool bit1) {
    float lo = bit0 ? v1 : v0;
    float hi = bit0 ? v3 : v2;
    return bit1 ? hi : lo;
}

// ---------------- Kernel 1: x-part of all 4 gate preactivations ----------------
// xpart[s][b][16] = emb[x[b,s]] @ W{f,i,u,o}[:, :256].T + bias + theta
// (gate-major j = g*4+jj). W slices live in registers; reduce-scatter via shfl.
__global__ __launch_bounds__(256) void k_embed(
    const int* __restrict__ x, const float* __restrict__ emb,
    const float* __restrict__ Wf, const float* __restrict__ bf,
    const float* __restrict__ Wi, const float* __restrict__ bi,
    const float* __restrict__ Wu, const float* __restrict__ bu,
    const float* __restrict__ Wo, const float* __restrict__ bo,
    const float* __restrict__ thf, const float* __restrict__ thi,
    const float* __restrict__ thu, const float* __restrict__ tho,
    float* __restrict__ xpart)
{
    const int lane = threadIdx.x & 63;
    const int wave_id = blockIdx.x * 4 + (threadIdx.x >> 6);  // 0..2047

    // lane owns embedding slice [4*lane, 4*lane+4)
    float4 Wreg[16];
    #pragma unroll
    for (int j = 0; j < 16; ++j) {
        const float* Wgp = (j < 8) ? ((j < 4) ? Wf : Wi) : ((j < 12) ? Wu : Wo);
        Wreg[j] = *(const float4*)(Wgp + (j & 3) * DIN + lane * 4);
    }
    // bias+theta for output index (lane&15)
    float biasv;
    {
        int j = lane & 15, jj = j & 3;
        const float* bp = (j < 8) ? ((j < 4) ? bf : bi) : ((j < 12) ? bu : bo);
        const float* tp = (j < 8) ? ((j < 4) ? thf : thi) : ((j < 12) ? thu : tho);
        biasv = bp[jj] + tp[jj];
    }

    const bool p0 = (lane & 1) != 0, p1 = (lane & 2) != 0,
               p2 = (lane & 4) != 0, p3 = (lane & 8) != 0;

    int row0 = wave_id * 16;
    for (int i = 0; i < 16; ++i) {
        int r = row0 + i;            // r = s*256 + b
        int b = r & 255, s = r >> 8;
        int tok = x[b * NS + s];
        float4 ev = *(const float4*)(emb + (size_t)tok * NE + lane * 4);

        float acc[16];
        #pragma unroll
        for (int j = 0; j < 16; ++j) {
            float4 wv = Wreg[j];
            acc[j] = fmaf(ev.x, wv.x, fmaf(ev.y, wv.y, fmaf(ev.z, wv.z, ev.w * wv.w)));
        }
        // reduce-scatter: final lane l holds sum for j = l&15
        float t8[8];
        #pragma unroll
        for (int i2 = 0; i2 < 8; ++i2) {
            float keep = p0 ? acc[2 * i2 + 1] : acc[2 * i2];
            float send = p0 ? acc[2 * i2] : acc[2 * i2 + 1];
            t8[i2] = keep + __shfl_xor(send, 1, 64);
        }
        float t4[4];
        #pragma unroll
        for (int i2 = 0; i2 < 4; ++i2) {
            float keep = p1 ? t8[2 * i2 + 1] : t8[2 * i2];
            float send = p1 ? t8[2 * i2] : t8[2 * i2 + 1];
            t4[i2] = keep + __shfl_xor(send, 2, 64);
        }
        float t2[2];
        #pragma unroll
        for (int i2 = 0; i2 < 2; ++i2) {
            float keep = p2 ? t4[2 * i2 + 1] : t4[2 * i2];
            float send = p2 ? t4[2 * i2] : t4[2 * i2 + 1];
            t2[i2] = keep + __shfl_xor(send, 4, 64);
        }
        float keep = p3 ? t2[1] : t2[0];
        float send = p3 ? t2[0] : t2[1];
        float t1 = keep + __shfl_xor(send, 8, 64);
        t1 += __shfl_xor(t1, 16, 64);
        t1 += __shfl_xor(t1, 32, 64);

        if (lane < 16)
            xpart[(size_t)r * 16 + lane] = t1 + biasv;
    }
}

// ---------------- Kernel 2: serial LSTM recurrence, 4 lanes per batch ----------------
// lane = gate g (also state index j). q products: q0=c1c2c3, q1=c0c1, q2=c0c1c2, q3=c0c1c2c3.
__global__ __launch_bounds__(64) void k_recur(
    const float* __restrict__ Wf, const float* __restrict__ Wi,
    const float* __restrict__ Wu, const float* __restrict__ Wo,
    const float* __restrict__ xpart, float* __restrict__ hs)
{
    const int lane = threadIdx.x;
    const int g = lane & 3;
    const int b = blockIdx.x * 16 + (lane >> 2);

    // pre-permuted recurrent weights: Wp[j'][k] = W_g[j'][256 + (g^k)]
    const float* Wg = (g == 0) ? Wf : ((g == 1) ? Wi : ((g == 2) ? Wu : Wo));
    float Wp[4][4];
    #pragma unroll
    for (int j2 = 0; j2 < 4; ++j2)
        #pragma unroll
        for (int k = 0; k < 4; ++k)
            Wp[j2][k] = Wg[j2 * DIN + 256 + (g ^ k)];

    const bool b0 = (g & 1) != 0, b1 = (g & 2) != 0;
    // uniform activation: act(q) = bas + mlt*tanh(scl*q)
    const float scl = (g == 2) ? 1.0f : 0.5f;
    const float mlt = (g == 2) ? 1.0f : 0.5f;
    const float bas = (g == 2) ? 0.0f : 0.5f;

    float c = 0.0f;
    float hr0 = 0.f, hr1 = 0.f, hr2 = 0.f, hr3 = 0.f;  // hr[k] = h[g^k]

    const float4* xp = (const float4*)xpart;  // index (s*NB+b)*4 + g
    float4 xa = xp[(size_t)b * 4 + g];
    float4 xb = xp[(size_t)(NB + b) * 4 + g];

    for (int s = 0; s < NS; ++s) {
        float4 xc = xa;
        xa = xb;
        if (s + 2 < NS) xb = xp[((size_t)(s + 2) * NB + b) * 4 + g];

        float a0 = xc.x + Wp[0][0] * hr0 + Wp[0][1] * hr1 + Wp[0][2] * hr2 + Wp[0][3] * hr3;
        float a1 = xc.y + Wp[1][0] * hr0 + Wp[1][1] * hr1 + Wp[1][2] * hr2 + Wp[1][3] * hr3;
        float a2 = xc.z + Wp[2][0] * hr0 + Wp[2][1] * hr1 + Wp[2][2] * hr2 + Wp[2][3] * hr3;
        float a3 = xc.w + Wp[3][0] * hr0 + Wp[3][1] * hr1 + Wp[3][2] * hr2 + Wp[3][3] * hr3;

        float c0 = __cosf(a0), c1 = __cosf(a1), c2 = __cosf(a2), c3 = __cosf(a3);
        float t  = c2 * c3;
        float q1 = c0 * c1;
        float q0 = c1 * t;
        float q2 = q1 * c2;
        float q3 = q1 * t;

        float A0 = fmaf(mlt, tanh_cf(scl * q0), bas);
        float A1 = fmaf(mlt, tanh_cf(scl * q1), bas);
        float A2 = fmaf(mlt, tanh_cf(scl * q2), bas);
        float A3 = fmaf(mlt, tanh_cf(scl * q3), bas);

        // 4x4 lane transpose: round k sends A[g^k]; lane j receives act[j^k][j]
        float r1 = DPP_XOR1(sel4f(A0, A1, A2, A3, !b0,  b1));
        float r2 = DPP_XOR2(sel4f(A0, A1, A2, A3,  b0, !b1));
        float r3 = DPP_XOR3(sel4f(A0, A1, A2, A3, !b0, !b1));
        float r0 = sel4f(A0, A1, A2, A3, b0, b1);  // own act[j][j]

        // role r lives in recv[k = g^r]
        float fv = sel4f(r0, r1, r2, r3,  b0,  b1);
        float iv = sel4f(r0, r1, r2, r3, !b0,  b1);
        float uv = sel4f(r0, r1, r2, r3,  b0, !b1);
        float ov = sel4f(r0, r1, r2, r3, !b0, !b1);

        c = fmaf(fv, c, iv * uv);
        float hn = ov * tanh_cf(c);
        hs[((size_t)s * NB + b) * 4 + g] = hn;

        hr0 = hn;
        hr1 = DPP_XOR1(hn);
        hr2 = DPP_XOR2(hn);
        hr3 = DPP_XOR3(hn);
    }
}

// ---------------- Kernel 3: logits + log_softmax ----------------
__global__ __launch_bounds__(256) void k_out(
    const float* __restrict__ hs, const float* __restrict__ Wc,
    const float* __restrict__ bc, float* __restrict__ out)
{
    int gtid = blockIdx.x * 256 + threadIdx.x;
    int r = gtid >> 3;     // r = b*S + s
    int lr = gtid & 7;
    if (r >= NB * NS) return;
    int b = r >> 7, s = r & 127;
    float4 h = *(const float4*)(hs + ((size_t)s * NB + b) * 4);
    float l[4];
    #pragma unroll
    for (int k = 0; k < 4; ++k) {
        int t = lr * 4 + k;
        float4 w = *(const float4*)(Wc + t * 4);
        l[k] = bc[t] + w.x * h.x + w.y * h.y + w.z * h.z + w.w * h.w;
    }
    float m = fmaxf(fmaxf(l[0], l[1]), fmaxf(l[2], l[3]));
    #pragma unroll
    for (int msk = 1; msk < 8; msk <<= 1)
        m = fmaxf(m, __shfl_xor(m, msk, 64));
    float sum = 0.f;
    #pragma unroll
    for (int k = 0; k < 4; ++k)
        sum += __expf(l[k] - m);
    #pragma unroll
    for (int msk = 1; msk < 8; msk <<= 1)
        sum += __shfl_xor(sum, msk, 64);
    float lse = __logf(sum);
    float4 o;
    o.x = l[0] - m - lse;
    o.y = l[1] - m - lse;
    o.z = l[2] - m - lse;
    o.w = l[3] - m - lse;
    *(float4*)(out + (size_t)r * 32 + lr * 4) = o;
}

extern "C" void kernel_launch(void* const* d_in, const int* in_sizes, int n_in,
                              void* d_out, int out_size, void* d_ws, size_t ws_size,
                              hipStream_t stream) {
    const int*   x   = (const int*)d_in[0];
    const float* emb = (const float*)d_in[1];
    const float* Wf  = (const float*)d_in[2];
    const float* bf  = (const float*)d_in[3];
    const float* Wi  = (const float*)d_in[4];
    const float* bi  = (const float*)d_in[5];
    const float* Wu  = (const float*)d_in[6];
    const float* bu  = (const float*)d_in[7];
    const float* Wo  = (const float*)d_in[8];
    const float* bo  = (const float*)d_in[9];
    const float* thf = (const float*)d_in[10];
    const float* thi = (const float*)d_in[11];
    const float* thu = (const float*)d_in[12];
    const float* tho = (const float*)d_in[13];
    const float* Wc  = (const float*)d_in[14];
    const float* bc  = (const float*)d_in[15];
    float* out = (float*)d_out;

    float* xpart = (float*)d_ws;                    // [S][B][16]  2 MB
    float* hs    = xpart + (size_t)NS * NB * 16;    // [S][B][4]   512 KB

    k_embed<<<512, 256, 0, stream>>>(x, emb, Wf, bf, Wi, bi, Wu, bu, Wo, bo,
                                     thf, thi, thu, tho, xpart);
    k_recur<<<16, 64, 0, stream>>>(Wf, Wi, Wu, Wo, xpart, hs);
    k_out<<<1024, 256, 0, stream>>>(hs, Wc, bc, out);
}

// Round 3
// 55.570 us; speedup vs baseline: 4.1005x; 1.6340x over previous
//
#include <hip/hip_runtime.h>
#include <math.h>

constexpr int NB = 256;   // batch
constexpr int NS = 128;   // seq len
constexpr int NE = 256;   // embed dim
constexpr int DIN = 260;  // E + H

// ---------- fast primitives ----------
__device__ __forceinline__ float rcp_fast(float x) {
#if __has_builtin(__builtin_amdgcn_rcpf)
    return __builtin_amdgcn_rcpf(x);
#else
    return 1.0f / x;
#endif
}

#if __has_builtin(__builtin_amdgcn_mov_dpp)
#define DPP_XOR1(x) __int_as_float(__builtin_amdgcn_mov_dpp(__float_as_int(x), 0xB1, 0xF, 0xF, true))
#define DPP_XOR2(x) __int_as_float(__builtin_amdgcn_mov_dpp(__float_as_int(x), 0x4E, 0xF, 0xF, true))
#define DPP_XOR3(x) __int_as_float(__builtin_amdgcn_mov_dpp(__float_as_int(x), 0x1B, 0xF, 0xF, true))
#else
#define DPP_XOR1(x) __shfl_xor((x), 1, 64)
#define DPP_XOR2(x) __shfl_xor((x), 2, 64)
#define DPP_XOR3(x) __shfl_xor((x), 3, 64)
#endif

// Lambert continued-fraction tanh, exact-integer coeffs.
// |err| ~1e-7 on [-1,1], ~2e-5 at |y|=3. No exp; one v_rcp.
__device__ __forceinline__ float tanh_cf(float y) {
    float w = y * y;
    float num = y * fmaf(fmaf(21.0f, w, 1260.0f), w, 10395.0f);
    float den = fmaf(fmaf(w + 210.0f, w, 4725.0f), w, 10395.0f);
    return num * rcp_fast(den);
}

__device__ __forceinline__ float sel4f(float v0, float v1, float v2, float v3,
                                       bool bit0, bool bit1) {
    float lo = bit0 ? v1 : v0;
    float hi = bit0 ? v3 : v2;
    return bit1 ? hi : lo;
}

// ---------------- Kernel 1: x-part of all 4 gate preactivations ----------------
__global__ __launch_bounds__(256) void k_embed(
    const int* __restrict__ x, const float* __restrict__ emb,
    const float* __restrict__ Wf, const float* __restrict__ bf,
    const float* __restrict__ Wi, const float* __restrict__ bi,
    const float* __restrict__ Wu, const float* __restrict__ bu,
    const float* __restrict__ Wo, const float* __restrict__ bo,
    const float* __restrict__ thf, const float* __restrict__ thi,
    const float* __restrict__ thu, const float* __restrict__ tho,
    float* __restrict__ xpart)
{
    const int lane = threadIdx.x & 63;
    const int wave_id = blockIdx.x * 4 + (threadIdx.x >> 6);  // 0..2047

    float4 Wreg[16];
    #pragma unroll
    for (int j = 0; j < 16; ++j) {
        const float* Wgp = (j < 8) ? ((j < 4) ? Wf : Wi) : ((j < 12) ? Wu : Wo);
        Wreg[j] = *(const float4*)(Wgp + (j & 3) * DIN + lane * 4);
    }
    float biasv;
    {
        int j = lane & 15, jj = j & 3;
        const float* bp = (j < 8) ? ((j < 4) ? bf : bi) : ((j < 12) ? bu : bo);
        const float* tp = (j < 8) ? ((j < 4) ? thf : thi) : ((j < 12) ? thu : tho);
        biasv = bp[jj] + tp[jj];
    }

    const bool p0 = (lane & 1) != 0, p1 = (lane & 2) != 0,
               p2 = (lane & 4) != 0, p3 = (lane & 8) != 0;

    int row0 = wave_id * 16;
    for (int i = 0; i < 16; ++i) {
        int r = row0 + i;            // r = s*256 + b
        int b = r & 255, s = r >> 8;
        int tok = x[b * NS + s];
        float4 ev = *(const float4*)(emb + (size_t)tok * NE + lane * 4);

        float acc[16];
        #pragma unroll
        for (int j = 0; j < 16; ++j) {
            float4 wv = Wreg[j];
            acc[j] = fmaf(ev.x, wv.x, fmaf(ev.y, wv.y, fmaf(ev.z, wv.z, ev.w * wv.w)));
        }
        float t8[8];
        #pragma unroll
        for (int i2 = 0; i2 < 8; ++i2) {
            float keep = p0 ? acc[2 * i2 + 1] : acc[2 * i2];
            float send = p0 ? acc[2 * i2] : acc[2 * i2 + 1];
            t8[i2] = keep + __shfl_xor(send, 1, 64);
        }
        float t4[4];
        #pragma unroll
        for (int i2 = 0; i2 < 4; ++i2) {
            float keep = p1 ? t8[2 * i2 + 1] : t8[2 * i2];
            float send = p1 ? t8[2 * i2] : t8[2 * i2 + 1];
            t4[i2] = keep + __shfl_xor(send, 2, 64);
        }
        float t2[2];
        #pragma unroll
        for (int i2 = 0; i2 < 2; ++i2) {
            float keep = p2 ? t4[2 * i2 + 1] : t4[2 * i2];
            float send = p2 ? t4[2 * i2] : t4[2 * i2 + 1];
            t2[i2] = keep + __shfl_xor(send, 4, 64);
        }
        float keep = p3 ? t2[1] : t2[0];
        float send = p3 ? t2[0] : t2[1];
        float t1 = keep + __shfl_xor(send, 8, 64);
        t1 += __shfl_xor(t1, 16, 64);
        t1 += __shfl_xor(t1, 32, 64);

        if (lane < 16)
            xpart[(size_t)r * 16 + lane] = t1 + biasv;
    }
}

// ---------------- Kernel 2: serial LSTM recurrence, 4 lanes per batch ----------------
// lane = gate g (also state index j). Deep register prefetch: 2 chunk sets of
// 8 float4 (statically named), loads for chunk k+2 interleave with chunk k's
// compute -> prefetch distance ~15 steps (~2400 cyc) >> HBM latency.
__global__ __launch_bounds__(64) void k_recur(
    const float* __restrict__ Wf, const float* __restrict__ Wi,
    const float* __restrict__ Wu, const float* __restrict__ Wo,
    const float* __restrict__ xpart, float* __restrict__ hs)
{
    const int lane = threadIdx.x;
    const int g = lane & 3;
    const int b = blockIdx.x * 16 + (lane >> 2);

    // pre-permuted recurrent weights: Wp[j'][k] = W_g[j'][256 + (g^k)]
    const float* Wg = (g == 0) ? Wf : ((g == 1) ? Wi : ((g == 2) ? Wu : Wo));
    float Wp[4][4];
    #pragma unroll
    for (int j2 = 0; j2 < 4; ++j2)
        #pragma unroll
        for (int k = 0; k < 4; ++k)
            Wp[j2][k] = Wg[j2 * DIN + 256 + (g ^ k)];

    const bool b0 = (g & 1) != 0, b1 = (g & 2) != 0;
    const float scl = (g == 2) ? 1.0f : 0.5f;
    const float mlt = (g == 2) ? 1.0f : 0.5f;
    const float bas = (g == 2) ? 0.0f : 0.5f;

    float c = 0.0f;
    float hr0 = 0.f, hr1 = 0.f, hr2 = 0.f, hr3 = 0.f;  // hr[k] = h[g^k]

    // per-lane base: element (s*256+b)*4+g of float4 array -> byte s*16384 + (b*4+g)*16
    const char* xbase = (const char*)xpart + (size_t)(b * 4 + g) * 16;
    float* hsbase = hs + (size_t)b * 4 + g;   // + s*1024 floats per step

#define LDX(CH, K) (*(const float4*)(xbase + (size_t)(((CH) * 8 + (K)) * 16384)))

#define QSTEP(XC, S) do {                                                   \
    float m0 = fmaf(Wp[0][2], hr2, Wp[0][3] * hr3);                         \
    float v0 = fmaf(Wp[0][1], hr1, m0);                                     \
    float u0 = fmaf(Wp[0][0], hr0, (XC).x);                                 \
    float a0 = u0 + v0;                                                     \
    float m1 = fmaf(Wp[1][2], hr2, Wp[1][3] * hr3);                         \
    float v1 = fmaf(Wp[1][1], hr1, m1);                                     \
    float u1 = fmaf(Wp[1][0], hr0, (XC).y);                                 \
    float a1 = u1 + v1;                                                     \
    float m2 = fmaf(Wp[2][2], hr2, Wp[2][3] * hr3);                         \
    float v2 = fmaf(Wp[2][1], hr1, m2);                                     \
    float u2 = fmaf(Wp[2][0], hr0, (XC).z);                                 \
    float a2 = u2 + v2;                                                     \
    float m3 = fmaf(Wp[3][2], hr2, Wp[3][3] * hr3);                         \
    float v3 = fmaf(Wp[3][1], hr1, m3);                                     \
    float u3 = fmaf(Wp[3][0], hr0, (XC).w);                                 \
    float a3 = u3 + v3;                                                     \
    float c0_ = __cosf(a0), c1_ = __cosf(a1), c2_ = __cosf(a2), c3_ = __cosf(a3); \
    float tt = c2_ * c3_;                                                   \
    float q1 = c0_ * c1_;                                                   \
    float q0 = c1_ * tt;                                                    \
    float q2 = q1 * c2_;                                                    \
    float q3 = q1 * tt;                                                     \
    float A0 = fmaf(mlt, tanh_cf(scl * q0), bas);                           \
    float A1 = fmaf(mlt, tanh_cf(scl * q1), bas);                           \
    float A2 = fmaf(mlt, tanh_cf(scl * q2), bas);                           \
    float A3 = fmaf(mlt, tanh_cf(scl * q3), bas);                           \
    float r1 = DPP_XOR1(sel4f(A0, A1, A2, A3, !b0,  b1));                   \
    float r2 = DPP_XOR2(sel4f(A0, A1, A2, A3,  b0, !b1));                   \
    float r3 = DPP_XOR3(sel4f(A0, A1, A2, A3, !b0, !b1));                   \
    float r0 = sel4f(A0, A1, A2, A3, b0, b1);                               \
    float fv = sel4f(r0, r1, r2, r3,  b0,  b1);                             \
    float iv = sel4f(r0, r1, r2, r3, !b0,  b1);                             \
    float uv = sel4f(r0, r1, r2, r3,  b0, !b1);                             \
    float ov = sel4f(r0, r1, r2, r3, !b0, !b1);                             \
    c = fmaf(fv, c, iv * uv);                                               \
    float hn = ov * tanh_cf(c);                                             \
    hsbase[(size_t)(S) * 1024] = hn;                                        \
    hr0 = hn;                                                               \
    hr1 = DPP_XOR1(hn);                                                     \
    hr2 = DPP_XOR2(hn);                                                     \
    hr3 = DPP_XOR3(hn);                                                     \
} while (0)

    // preload chunks 0 and 1
    float4 xA0 = LDX(0, 0), xA1 = LDX(0, 1), xA2 = LDX(0, 2), xA3 = LDX(0, 3);
    float4 xA4 = LDX(0, 4), xA5 = LDX(0, 5), xA6 = LDX(0, 6), xA7 = LDX(0, 7);
    float4 xB0 = LDX(1, 0), xB1 = LDX(1, 1), xB2 = LDX(1, 2), xB3 = LDX(1, 3);
    float4 xB4 = LDX(1, 4), xB5 = LDX(1, 5), xB6 = LDX(1, 6), xB7 = LDX(1, 7);

    for (int cp = 0; cp < 8; ++cp) {
        int s0 = cp * 16;
        int chA = (cp * 2 + 2) & 15;   // cp==7 wraps to 0: redundant L2-hit reload, branch-free
        int chB = (cp * 2 + 3) & 15;
        QSTEP(xA0, s0 + 0);  xA0 = LDX(chA, 0);
        QSTEP(xA1, s0 + 1);  xA1 = LDX(chA, 1);
        QSTEP(xA2, s0 + 2);  xA2 = LDX(chA, 2);
        QSTEP(xA3, s0 + 3);  xA3 = LDX(chA, 3);
        QSTEP(xA4, s0 + 4);  xA4 = LDX(chA, 4);
        QSTEP(xA5, s0 + 5);  xA5 = LDX(chA, 5);
        QSTEP(xA6, s0 + 6);  xA6 = LDX(chA, 6);
        QSTEP(xA7, s0 + 7);  xA7 = LDX(chA, 7);
        QSTEP(xB0, s0 + 8);  xB0 = LDX(chB, 0);
        QSTEP(xB1, s0 + 9);  xB1 = LDX(chB, 1);
        QSTEP(xB2, s0 + 10); xB2 = LDX(chB, 2);
        QSTEP(xB3, s0 + 11); xB3 = LDX(chB, 3);
        QSTEP(xB4, s0 + 12); xB4 = LDX(chB, 4);
        QSTEP(xB5, s0 + 13); xB5 = LDX(chB, 5);
        QSTEP(xB6, s0 + 14); xB6 = LDX(chB, 6);
        QSTEP(xB7, s0 + 15); xB7 = LDX(chB, 7);
    }
#undef QSTEP
#undef LDX
}

// ---------------- Kernel 3: logits + log_softmax ----------------
__global__ __launch_bounds__(256) void k_out(
    const float* __restrict__ hs, const float* __restrict__ Wc,
    const float* __restrict__ bc, float* __restrict__ out)
{
    int gtid = blockIdx.x * 256 + threadIdx.x;
    int r = gtid >> 3;     // r = b*S + s
    int lr = gtid & 7;
    if (r >= NB * NS) return;
    int b = r >> 7, s = r & 127;
    float4 h = *(const float4*)(hs + ((size_t)s * NB + b) * 4);
    float l[4];
    #pragma unroll
    for (int k = 0; k < 4; ++k) {
        int t = lr * 4 + k;
        float4 w = *(const float4*)(Wc + t * 4);
        l[k] = bc[t] + w.x * h.x + w.y * h.y + w.z * h.z + w.w * h.w;
    }
    float m = fmaxf(fmaxf(l[0], l[1]), fmaxf(l[2], l[3]));
    #pragma unroll
    for (int msk = 1; msk < 8; msk <<= 1)
        m = fmaxf(m, __shfl_xor(m, msk, 64));
    float sum = 0.f;
    #pragma unroll
    for (int k = 0; k < 4; ++k)
        sum += __expf(l[k] - m);
    #pragma unroll
    for (int msk = 1; msk < 8; msk <<= 1)
        sum += __shfl_xor(sum, msk, 64);
    float lse = __logf(sum);
    float4 o;
    o.x = l[0] - m - lse;
    o.y = l[1] - m - lse;
    o.z = l[2] - m - lse;
    o.w = l[3] - m - lse;
    *(float4*)(out + (size_t)r * 32 + lr * 4) = o;
}

extern "C" void kernel_launch(void* const* d_in, const int* in_sizes, int n_in,
                              void* d_out, int out_size, void* d_ws, size_t ws_size,
                              hipStream_t stream) {
    const int*   x   = (const int*)d_in[0];
    const float* emb = (const float*)d_in[1];
    const float* Wf  = (const float*)d_in[2];
    const float* bf  = (const float*)d_in[3];
    const float* Wi  = (const float*)d_in[4];
    const float* bi  = (const float*)d_in[5];
    const float* Wu  = (const float*)d_in[6];
    const float* bu  = (const float*)d_in[7];
    const float* Wo  = (const float*)d_in[8];
    const float* bo  = (const float*)d_in[9];
    const float* thf = (const float*)d_in[10];
    const float* thi = (const float*)d_in[11];
    const float* thu = (const float*)d_in[12];
    const float* tho = (const float*)d_in[13];
    const float* Wc  = (const float*)d_in[14];
    const float* bc  = (const float*)d_in[15];
    float* out = (float*)d_out;

    float* xpart = (float*)d_ws;                    // [S][B][16]  2 MB
    float* hs    = xpart + (size_t)NS * NB * 16;    // [S][B][4]   512 KB

    k_embed<<<512, 256, 0, stream>>>(x, emb, Wf, bf, Wi, bi, Wu, bu, Wo, bo,
                                     thf, thi, thu, tho, xpart);
    k_recur<<<16, 64, 0, stream>>>(Wf, Wi, Wu, Wo, xpart, hs);
    k_out<<<1024, 256, 0, stream>>>(hs, Wc, bc, out);
}